// Round 4
// baseline (14.590 us; speedup 1.0000x reference)
//
#include <hip/hip_runtime.h>

// CRF score: out = (sum_m emissions[b,s,tag] + sum_pairs transitions[t0,t1]) / sum(m)
// B=512, S=512, T=128 hardcoded. 2 elems/thread, 512 blocks x 256 threads.
// SINGLE dispatch: per-block partials + flag release; block 0 spin-waits
// (acquire) on all flags, reduces, writes scalar, resets flags to 0.
// Initial-value-independent (works with 0xAA poison in d_ws).

constexpr int S = 512;
constexpr int TOTAL = 512 * 512;          // B*S
constexpr int NBLK = TOTAL / (256 * 2);   // 512

__global__ __launch_bounds__(256) void crf_fused_kernel(
        const float* __restrict__ emissions,
        const int* __restrict__ tags,
        const int* __restrict__ mask,
        const float* __restrict__ transitions,
        double* __restrict__ part_val,
        unsigned int* __restrict__ part_cnt,
        unsigned int* __restrict__ flags,
        float* __restrict__ out) {
    int gid = blockIdx.x * 256 + threadIdx.x;     // 0 .. TOTAL/2-1
    int idx = gid << 1;                           // first of 2 consecutive elements

    int2 tg = ((const int2*)tags)[gid];
    int2 mk = ((const int2*)mask)[gid];

    float contrib = 0.0f;
    unsigned int cnt = 0;

    // emissions gathers: offset = idx*128 + tag
    if (mk.x) { contrib += emissions[((size_t)idx << 7) + (size_t)tg.x]; ++cnt; }
    if (mk.y) { contrib += emissions[(((size_t)idx + 1) << 7) + (size_t)tg.y]; ++cnt; }

    // in-thread pair (idx, idx+1): idx even, never crosses a sequence boundary
    if (mk.x & mk.y) contrib += transitions[(tg.x << 7) + tg.y];

    // cross-thread pair (idx+1, idx+2): skip when idx+1 is last in sequence
    int s0 = idx & (S - 1);
    if (s0 != S - 2 && mk.y) {
        if (mask[idx + 2]) contrib += transitions[(tg.y << 7) + tags[idx + 2]];
    }

    // wave(64) reduction
    double val = (double)contrib;
    #pragma unroll
    for (int off = 32; off > 0; off >>= 1) {
        val += __shfl_down(val, off, 64);
        cnt += __shfl_down(cnt, off, 64);
    }

    __shared__ double s_val[4];
    __shared__ unsigned int s_cnt[4];
    int wave = threadIdx.x >> 6;
    int lane = threadIdx.x & 63;
    if (lane == 0) { s_val[wave] = val; s_cnt[wave] = cnt; }
    __syncthreads();

    if (threadIdx.x == 0) {
        part_val[blockIdx.x] = s_val[0] + s_val[1] + s_val[2] + s_val[3];
        part_cnt[blockIdx.x] = s_cnt[0] + s_cnt[1] + s_cnt[2] + s_cnt[3];
        // release: make the partial visible device-wide before the flag
        __hip_atomic_store(&flags[blockIdx.x], 1u, __ATOMIC_RELEASE,
                           __HIP_MEMORY_SCOPE_AGENT);
    }

    // ---- finalizer: block 0 waits for all partials, reduces, writes out ----
    if (blockIdx.x == 0) {
        int t = threadIdx.x;
        double v = 0.0;
        unsigned int c = 0;
        #pragma unroll
        for (int i = 0; i < NBLK / 256; ++i) {
            int j = t + i * 256;
            while (__hip_atomic_load(&flags[j], __ATOMIC_ACQUIRE,
                                     __HIP_MEMORY_SCOPE_AGENT) != 1u) { }
            v += part_val[j];
            c += part_cnt[j];
            // reset for the next graph replay (only this thread read flags[j])
            __hip_atomic_store(&flags[j], 0u, __ATOMIC_RELAXED,
                               __HIP_MEMORY_SCOPE_AGENT);
        }

        #pragma unroll
        for (int off = 32; off > 0; off >>= 1) {
            v += __shfl_down(v, off, 64);
            c += __shfl_down(c, off, 64);
        }
        __shared__ double f_val[4];
        __shared__ unsigned int f_cnt[4];
        if (lane == 0) { f_val[wave] = v; f_cnt[wave] = c; }
        __syncthreads();
        if (t == 0) {
            double vv = f_val[0] + f_val[1] + f_val[2] + f_val[3];
            unsigned int cc = f_cnt[0] + f_cnt[1] + f_cnt[2] + f_cnt[3];
            out[0] = (float)(vv / (double)cc);
        }
    }
}

extern "C" void kernel_launch(void* const* d_in, const int* in_sizes, int n_in,
                              void* d_out, int out_size, void* d_ws, size_t ws_size,
                              hipStream_t stream) {
    const float* emissions   = (const float*)d_in[0];
    const int*   tags        = (const int*)d_in[1];
    const int*   mask        = (const int*)d_in[2];
    const float* transitions = (const float*)d_in[3];
    float* out = (float*)d_out;

    double*       part_val = (double*)d_ws;
    unsigned int* part_cnt = (unsigned int*)((char*)d_ws + NBLK * sizeof(double));
    unsigned int* flags    = (unsigned int*)((char*)d_ws + NBLK * (sizeof(double) + sizeof(unsigned int)));

    crf_fused_kernel<<<NBLK, 256, 0, stream>>>(emissions, tags, mask, transitions,
                                               part_val, part_cnt, flags, out);
}

// Round 5
// 9.794 us; speedup vs baseline: 1.4897x; 1.4897x over previous
//
#include <hip/hip_runtime.h>

// CRF score: out = (sum_m emissions[b,s,tag] + sum_pairs transitions[t0,t1]) / sum(m)
// B=512, S=512, T=128 hardcoded. 2 elems/thread, 512 blocks x 256 threads.
// SINGLE dispatch with a cheap hand-rolled barrier:
//   - partials stored as RELAXED agent-scope atomics (sc1 -> coherence point,
//     no L2 residency, no wbl2)
//   - s_waitcnt vmcnt(0) orders partial-store before flag-store
//   - block 0 spins with RELAXED agent loads (sc1, no buffer_inv per poll)
// Flags are written to 1 every call and reset to 0 by block 0 -> poison-safe
// and deterministic across graph replays.

constexpr int S = 512;
constexpr int TOTAL = 512 * 512;          // B*S
constexpr int NBLK = TOTAL / (256 * 2);   // 512

__global__ __launch_bounds__(256) void crf_fused_kernel(
        const float* __restrict__ emissions,
        const int* __restrict__ tags,
        const int* __restrict__ mask,
        const float* __restrict__ transitions,
        double* __restrict__ part_val,
        unsigned int* __restrict__ part_cnt,
        unsigned int* __restrict__ flags,
        float* __restrict__ out) {
    int gid = blockIdx.x * 256 + threadIdx.x;     // 0 .. TOTAL/2-1
    int idx = gid << 1;                           // first of 2 consecutive elements

    int2 tg = ((const int2*)tags)[gid];
    int2 mk = ((const int2*)mask)[gid];

    float contrib = 0.0f;
    unsigned int cnt = 0;

    // emissions gathers: offset = idx*128 + tag
    if (mk.x) { contrib += emissions[((size_t)idx << 7) + (size_t)tg.x]; ++cnt; }
    if (mk.y) { contrib += emissions[(((size_t)idx + 1) << 7) + (size_t)tg.y]; ++cnt; }

    // in-thread pair (idx, idx+1): idx even, never crosses a sequence boundary
    if (mk.x & mk.y) contrib += transitions[(tg.x << 7) + tg.y];

    // cross-thread pair (idx+1, idx+2): skip when idx+1 is last in sequence
    int s0 = idx & (S - 1);
    if (s0 != S - 2 && mk.y) {
        if (mask[idx + 2]) contrib += transitions[(tg.y << 7) + tags[idx + 2]];
    }

    // wave(64) reduction
    double val = (double)contrib;
    #pragma unroll
    for (int off = 32; off > 0; off >>= 1) {
        val += __shfl_down(val, off, 64);
        cnt += __shfl_down(cnt, off, 64);
    }

    __shared__ double s_val[4];
    __shared__ unsigned int s_cnt[4];
    int wave = threadIdx.x >> 6;
    int lane = threadIdx.x & 63;
    if (lane == 0) { s_val[wave] = val; s_cnt[wave] = cnt; }
    __syncthreads();

    if (threadIdx.x == 0) {
        double bv = s_val[0] + s_val[1] + s_val[2] + s_val[3];
        unsigned int bc = s_cnt[0] + s_cnt[1] + s_cnt[2] + s_cnt[3];
        // sc1 stores: go straight to the coherence point (IF cache)
        __hip_atomic_store(&part_val[blockIdx.x], bv, __ATOMIC_RELAXED,
                           __HIP_MEMORY_SCOPE_AGENT);
        __hip_atomic_store(&part_cnt[blockIdx.x], bc, __ATOMIC_RELAXED,
                           __HIP_MEMORY_SCOPE_AGENT);
        // order: partials committed at coherence point before the flag
        asm volatile("s_waitcnt vmcnt(0)" ::: "memory");
        __hip_atomic_store(&flags[blockIdx.x], 1u, __ATOMIC_RELAXED,
                           __HIP_MEMORY_SCOPE_AGENT);
    }

    // ---- finalizer: block 0 waits for all partials, reduces, writes out ----
    if (blockIdx.x == 0) {
        __syncthreads();   // phase-1 shared reads done before reuse
        int t = threadIdx.x;
        double v = 0.0;
        unsigned int c = 0;
        #pragma unroll
        for (int i = 0; i < NBLK / 256; ++i) {
            int j = t + i * 256;
            while (__hip_atomic_load(&flags[j], __ATOMIC_RELAXED,
                                     __HIP_MEMORY_SCOPE_AGENT) != 1u) { }
            v += __hip_atomic_load(&part_val[j], __ATOMIC_RELAXED,
                                   __HIP_MEMORY_SCOPE_AGENT);
            c += __hip_atomic_load(&part_cnt[j], __ATOMIC_RELAXED,
                                   __HIP_MEMORY_SCOPE_AGENT);
            // reset for next graph replay (kernel-end ordering makes this safe)
            __hip_atomic_store(&flags[j], 0u, __ATOMIC_RELAXED,
                               __HIP_MEMORY_SCOPE_AGENT);
        }

        #pragma unroll
        for (int off = 32; off > 0; off >>= 1) {
            v += __shfl_down(v, off, 64);
            c += __shfl_down(c, off, 64);
        }
        __shared__ double f_val[4];
        __shared__ unsigned int f_cnt[4];
        if (lane == 0) { f_val[wave] = v; f_cnt[wave] = c; }
        __syncthreads();
        if (t == 0) {
            double vv = f_val[0] + f_val[1] + f_val[2] + f_val[3];
            unsigned int cc = f_cnt[0] + f_cnt[1] + f_cnt[2] + f_cnt[3];
            out[0] = (float)(vv / (double)cc);
        }
    }
}

extern "C" void kernel_launch(void* const* d_in, const int* in_sizes, int n_in,
                              void* d_out, int out_size, void* d_ws, size_t ws_size,
                              hipStream_t stream) {
    const float* emissions   = (const float*)d_in[0];
    const int*   tags        = (const int*)d_in[1];
    const int*   mask        = (const int*)d_in[2];
    const float* transitions = (const float*)d_in[3];
    float* out = (float*)d_out;

    double*       part_val = (double*)d_ws;
    unsigned int* part_cnt = (unsigned int*)((char*)d_ws + NBLK * sizeof(double));
    unsigned int* flags    = (unsigned int*)((char*)d_ws + NBLK * (sizeof(double) + sizeof(unsigned int)));

    crf_fused_kernel<<<NBLK, 256, 0, stream>>>(emissions, tags, mask, transitions,
                                               part_val, part_cnt, flags, out);
}